// Round 6
// baseline (1526.310 us; speedup 1.0000x reference)
//
#include <hip/hip_runtime.h>

// LSTM decoder B=2048, Z=64, A=8, H=512, T=64. Multi-launch, one kernel/step.
// gates = [h | z] @ [W_hh | W_ih_z]^T + bias ; bf16 MFMA 16x16x32.
// Round 6: occupancy push. Grid 512 WGs x 512 thr = 4 waves/SIMD (2 WG/CU).
// WG = 64 batch x 128 cols; wave = 32 batch x 32 cols (2Mx2N). Cell gates
// exchanged via padded f32 LDS buffer (wave owns 1 gate, cell needs 4).

#define HID   512
#define TSTEP 64
#define KCAT  576

typedef __attribute__((ext_vector_type(8))) short bf16x8;
typedef __attribute__((ext_vector_type(4))) float f32x4;

__device__ inline unsigned short f2bf(float f) {
  unsigned int u = __builtin_bit_cast(unsigned int, f);
  unsigned int r = (u + 0x7fffu + ((u >> 16) & 1u)) >> 16;
  return (unsigned short)r;
}
__device__ inline float sigm(float x) { return 1.0f / (1.0f + __expf(-x)); }
__device__ inline float tanh_f(float x) { return 1.0f - 2.0f / (__expf(2.0f * x) + 1.0f); }

__device__ inline void gl16(const unsigned short* g, unsigned short* l) {
  __builtin_amdgcn_global_load_lds(
      (const __attribute__((address_space(1))) unsigned int*)g,
      (__attribute__((address_space(3))) unsigned int*)l, 16, 0, 0);
}

// ---- prep: W_cat[n][0..575] = [W_hh[n][:] | W_ih[n][8..71]] bf16 ----
__global__ void k_prep_w(const float* __restrict__ whh, const float* __restrict__ wih,
                         unsigned short* __restrict__ wcat) {
  int c = blockIdx.x * 256 + threadIdx.x;
  if (c >= 2048 * 72) return;
  int n = c / 72, kc = (c % 72) * 8;
  unsigned short u[8];
#pragma unroll
  for (int e = 0; e < 8; ++e) {
    int k = kc + e;
    float v = (k < 512) ? whh[(size_t)n * 512 + k] : wih[(size_t)n * 72 + 8 + (k - 512)];
    u[e] = f2bf(v);
  }
  *(bf16x8*)&wcat[(size_t)n * KCAT + kc] = *(bf16x8*)u;
}

__global__ void k_prep_zb(const float* __restrict__ z, const float* __restrict__ bih,
                          const float* __restrict__ bhh, unsigned short* __restrict__ zbf,
                          float* __restrict__ bias) {
  int c = blockIdx.x * 256 + threadIdx.x;
  if (c < 16384) {
    int row = c >> 3, kc = (c & 7) * 8;
    unsigned short u[8];
#pragma unroll
    for (int e = 0; e < 8; ++e) u[e] = f2bf(z[(size_t)row * 64 + kc + e]);
    *(bf16x8*)&zbf[(size_t)row * 64 + kc] = *(bf16x8*)u;
  } else if (c < 16384 + 2048) {
    int n = c - 16384;
    bias[n] = bih[n] + bhh[n];
  }
}

__global__ void k_initout(const float* __restrict__ bout, float* __restrict__ out) {
  int g = blockIdx.x * 256 + threadIdx.x;
  out[g] = bout[g & 7];
}

// A-fragment loads: 2 M-frags x 2 ks, direct from global (h or z)
__device__ inline void aload4(bf16x8 d[4], const unsigned short* hrd,
                              const unsigned short* zb, int kk, int arow,
                              int cl, int q8) {
  if (kk < 8) {
    const unsigned short* p = hrd + (size_t)(arow + cl) * HID + kk * 64 + q8 * 8;
#pragma unroll
    for (int m = 0; m < 2; ++m) {
      d[m * 2 + 0] = *(const bf16x8*)(p + m * 16 * HID);
      d[m * 2 + 1] = *(const bf16x8*)(p + m * 16 * HID + 32);
    }
  } else {
    const unsigned short* p = zb + (size_t)(arow + cl) * 64 + q8 * 8;
#pragma unroll
    for (int m = 0; m < 2; ++m) {
      d[m * 2 + 0] = *(const bf16x8*)(p + m * 16 * 64);
      d[m * 2 + 1] = *(const bf16x8*)(p + m * 16 * 64 + 32);
    }
  }
}

// ---- one step. grid (nt 16, bt 32), 512 thr (8 waves = 2 mg x 4 nw). ----
template <int USE_PART>
__global__ __launch_bounds__(512, 4) void k_step(
    const unsigned short* __restrict__ hprev, unsigned short* __restrict__ hnext,
    const unsigned short* __restrict__ wcat, const unsigned short* __restrict__ zbf,
    const float* __restrict__ bias, float* __restrict__ cst,
    const float* __restrict__ wout, float* __restrict__ dst, int t) {
  __shared__ unsigned short Bb[2][128 * 64];   // B chunk dbuf, 16 KB each
  __shared__ float sg[128 * 68];               // gate exchange [col][batch+4pad]
  __shared__ unsigned short hO[64 * 40];       // h tile
  __shared__ unsigned short wo16[16 * 32];     // W_out slice bf16 (rows 8..15 = 0)

  const int nt = blockIdx.x, bt = blockIdx.y;
  const int tid = threadIdx.x;
  const int lane = tid & 63;
  const int wv = tid >> 6;                     // 0..7
  const int nw = wv & 3, mg = wv >> 2;
  const int cl = lane & 15, q8 = lane >> 4;
  const int b0 = bt * 64, j0 = nt * 32;
  const int arow = b0 + mg * 32;

  wo16[tid & 511] = ((tid >> 5) < 8) ? f2bf(wout[(size_t)(tid >> 5) * HID + j0 + (tid & 31)])
                                     : (unsigned short)0;

  // B staging: 128 rows x 64 k per chunk; thread covers 2 x 16B; XOR-swizzled src
  const int sr0 = wv * 8 + (lane >> 3);
  const int sr1 = 64 + sr0;
  const int ss = lane & 7;
  const int sn0 = (sr0 >> 5) * HID + j0 + (sr0 & 31);
  const int sn1 = (sr1 >> 5) * HID + j0 + (sr1 & 31);
  const unsigned short* wsrc0 = wcat + (size_t)sn0 * KCAT + (ss ^ (sr0 & 7)) * 8;
  const unsigned short* wsrc1 = wcat + (size_t)sn1 * KCAT + (ss ^ (sr1 & 7)) * 8;
#define STAGE(BUF, CHUNK) do { \
    gl16(wsrc0 + (CHUNK) * 64, &Bb[BUF][wv * 512]); \
    gl16(wsrc1 + (CHUNK) * 64, &Bb[BUF][4096 + wv * 512]); } while (0)

  // acc init = bias (wave cols: nw*32 + n*16 + cl)
  f32x4 acc[2][2];
#pragma unroll
  for (int n = 0; n < 2; ++n) {
    int c = nw * 32 + n * 16 + cl;
    float bv = bias[(c >> 5) * HID + j0 + (c & 31)];
    f32x4 v = {bv, bv, bv, bv};
    acc[n][0] = v; acc[n][1] = v;
  }

  const int kk0 = t ? 0 : 8;                   // t=0: only z chunk
  STAGE(0, kk0);
  bf16x8 aa[4], nn[4];
  aload4(aa, hprev, zbf, kk0, arow, cl, q8);
  __syncthreads();

  for (int kk = kk0; kk <= 8; ++kk) {
    const int bu = (kk - kk0) & 1;
    if (kk < 8) {
      STAGE(bu ^ 1, kk + 1);
      aload4(nn, hprev, zbf, kk + 1, arow, cl, q8);
    }
    const unsigned short* Bl = Bb[bu];
#pragma unroll
    for (int ks = 0; ks < 2; ++ks) {
#pragma unroll
      for (int n = 0; n < 2; ++n) {
        int rb = nw * 32 + n * 16 + cl;
        bf16x8 bf = *(const bf16x8*)&Bl[rb * 64 + ((ks * 4 + q8) ^ (cl & 7)) * 8];
#pragma unroll
        for (int m = 0; m < 2; ++m)
          acc[n][m] = __builtin_amdgcn_mfma_f32_16x16x32_bf16(aa[m * 2 + ks], bf, acc[n][m], 0, 0, 0);
      }
    }
    __syncthreads();
    if (kk < 8) {
#pragma unroll
      for (int i = 0; i < 4; ++i) aa[i] = nn[i];
    }
  }

  // ---- gate exchange: acc -> sg[col][batch_local] ----
#pragma unroll
  for (int n = 0; n < 2; ++n)
#pragma unroll
    for (int m = 0; m < 2; ++m) {
      int c = nw * 32 + n * 16 + cl;
      int bl = mg * 32 + m * 16 + q8 * 4;
      *(f32x4*)&sg[c * 68 + bl] = acc[n][m];
    }
  __syncthreads();

  // ---- cell: thread = (jj = tid&31, batch block bb4 = (tid>>5)*4) ----
  const int jj = tid & 31;
  const int bb4 = (tid >> 5) * 4;
  const size_t cbase = (((size_t)bt * 16 + nt) * 512 + tid) * 4;
  f32x4 cc = {0, 0, 0, 0};
  if (t > 0) cc = *(const f32x4*)&cst[cbase];
  {
    f32x4 gi = *(const f32x4*)&sg[(0 * 32 + jj) * 68 + bb4];
    f32x4 gf = *(const f32x4*)&sg[(1 * 32 + jj) * 68 + bb4];
    f32x4 gg = *(const f32x4*)&sg[(2 * 32 + jj) * 68 + bb4];
    f32x4 go = *(const f32x4*)&sg[(3 * 32 + jj) * 68 + bb4];
    f32x4 cn;
#pragma unroll
    for (int r = 0; r < 4; ++r) {
      float iv = sigm(gi[r]);
      float fv = sigm(gf[r]);
      float gv = tanh_f(gg[r]);
      float ov = sigm(go[r]);
      float cv = fv * cc[r] + iv * gv;
      cn[r] = cv;
      hO[(bb4 + r) * 40 + jj] = f2bf(ov * tanh_f(cv));
    }
    *(f32x4*)&cst[cbase] = cn;
  }
  __syncthreads();

  // ---- h -> global ping-pong (first 256 threads, 16B each) ----
  if (t < TSTEP - 1 && tid < 256) {
    int row = tid >> 2, sg4 = tid & 3;
    unsigned short tmp[8];
#pragma unroll
    for (int e = 0; e < 8; ++e) tmp[e] = hO[row * 40 + sg4 * 8 + e];
    *(int4*)&hnext[(size_t)(b0 + row) * HID + j0 + sg4 * 8] = *(int4*)tmp;
  }

  // ---- output projection via MFMA (waves 0..3, one 16-row block each) ----
  if (wv < 4) {
    bf16x8 bw = *(const bf16x8*)&wo16[cl * 32 + q8 * 8];
    bf16x8 ah = *(const bf16x8*)&hO[(wv * 16 + cl) * 40 + q8 * 8];
    f32x4 pr = {0, 0, 0, 0};
    pr = __builtin_amdgcn_mfma_f32_16x16x32_bf16(ah, bw, pr, 0, 0, 0);
    if (cl < 8) {
#pragma unroll
      for (int r = 0; r < 4; ++r) {
        int row = wv * 16 + q8 * 4 + r;
        if (USE_PART)
          dst[(size_t)nt * 1048576 + (size_t)(b0 + row) * 512 + t * 8 + cl] = pr[r];
        else
          atomicAdd(&dst[(size_t)(b0 + row) * 512 + t * 8 + cl], pr[r]);
      }
    }
  }
#undef STAGE
}

__global__ void k_final(const float* __restrict__ part, const float* __restrict__ bout,
                        float* __restrict__ out) {
  int g = blockIdx.x * 256 + threadIdx.x;      // (b*64+t)*8+a
  float s = bout[g & 7];
#pragma unroll
  for (int n = 0; n < 16; ++n) s += part[(size_t)n * 1048576 + g];
  out[g] = s;
}

extern "C" void kernel_launch(void* const* d_in, const int* in_sizes, int n_in,
                              void* d_out, int out_size, void* d_ws, size_t ws_size,
                              hipStream_t stream) {
  const float* z    = (const float*)d_in[0];
  const float* wih  = (const float*)d_in[1];
  const float* whh  = (const float*)d_in[2];
  const float* bih  = (const float*)d_in[3];
  const float* bhh  = (const float*)d_in[4];
  const float* wout = (const float*)d_in[5];
  const float* bout = (const float*)d_in[6];
  float* out = (float*)d_out;

  char* ws = (char*)d_ws;
  unsigned short* wcat = (unsigned short*)(ws);              // 2,359,296
  unsigned short* zbf  = (unsigned short*)(ws + 2359296);    //   262,144
  float* bias          = (float*)(ws + 2621440);             //     8,192
  unsigned short* h0   = (unsigned short*)(ws + 2629632);    // 2,097,152
  unsigned short* h1   = (unsigned short*)(ws + 4726784);    // 2,097,152
  float* cst           = (float*)(ws + 6823936);             // 4,194,304
  float* part          = (float*)(ws + 11018240);            // 67,108,864
  const bool use_part = ws_size >= 11018240ull + 67108864ull;

  k_prep_w<<<dim3(576), dim3(256), 0, stream>>>(whh, wih, wcat);
  k_prep_zb<<<dim3(72), dim3(256), 0, stream>>>(z, bih, bhh, zbf, bias);
  if (!use_part) k_initout<<<dim3(4096), dim3(256), 0, stream>>>(bout, out);

  for (int t = 0; t < TSTEP; ++t) {
    const unsigned short* hp = (t & 1) ? h0 : h1;
    unsigned short* hn = (t & 1) ? h1 : h0;
    if (use_part)
      k_step<1><<<dim3(16, 32), dim3(512), 0, stream>>>(hp, hn, wcat, zbf, bias, cst, wout, part, t);
    else
      k_step<0><<<dim3(16, 32), dim3(512), 0, stream>>>(hp, hn, wcat, zbf, bias, cst, wout, out, t);
  }
  if (use_part) k_final<<<dim3(4096), dim3(256), 0, stream>>>(part, bout, out);
}

// Round 7
// 1096.583 us; speedup vs baseline: 1.3919x; 1.3919x over previous
//
#include <hip/hip_runtime.h>

// LSTM decoder B=2048, Z=64, A=8, H=512, T=64. Multi-launch (kernel boundary =
// cheapest grid barrier on MI355X; persistence measured 4-7x worse, r2/r4).
// gates = [h | z] @ [W_hh | W_ih_z]^T + bias, K = 576, bf16 MFMA 16x16x32.
// A (h) and B (W) both staged via global_load_lds(16B), XOR-swizzled source,
// conflict-free ds_read_b128. Output projection for h_t fused into step t+1
// (A-tile IS h_t): no partials, no atomics, no final reduce.

#define HID   512
#define TSTEP 64
#define KCAT  576

typedef __attribute__((ext_vector_type(8))) short bf16x8;
typedef __attribute__((ext_vector_type(4))) float f32x4;

__device__ inline unsigned short f2bf(float f) {
  unsigned int u = __builtin_bit_cast(unsigned int, f);
  unsigned int r = (u + 0x7fffu + ((u >> 16) & 1u)) >> 16;
  return (unsigned short)r;
}
__device__ inline float sigm(float x) { return 1.0f / (1.0f + __expf(-x)); }
__device__ inline float tanh_f(float x) { return 1.0f - 2.0f / (__expf(2.0f * x) + 1.0f); }

__device__ inline void gl16(const unsigned short* g, unsigned short* l) {
  __builtin_amdgcn_global_load_lds(
      (const __attribute__((address_space(1))) unsigned int*)g,
      (__attribute__((address_space(3))) unsigned int*)l, 16, 0, 0);
}

// ---- merged prep: wcat, zbf, bias, wob (W_out bf16, 16 rows, 8..15 zero) ----
__global__ void k_prep(const float* __restrict__ z, const float* __restrict__ wih,
                       const float* __restrict__ whh, const float* __restrict__ bih,
                       const float* __restrict__ bhh, const float* __restrict__ wout,
                       unsigned short* __restrict__ wcat, unsigned short* __restrict__ zbf,
                       float* __restrict__ bias, unsigned short* __restrict__ wob) {
  int c = blockIdx.x * 256 + threadIdx.x;
  if (c < 147456) {                              // wcat: 2048 rows x 72 chunks
    int n = c / 72, kc = (c % 72) * 8;
    unsigned short u[8];
#pragma unroll
    for (int e = 0; e < 8; ++e) {
      int k = kc + e;
      float v = (k < 512) ? whh[(size_t)n * 512 + k] : wih[(size_t)n * 72 + 8 + (k - 512)];
      u[e] = f2bf(v);
    }
    *(bf16x8*)&wcat[(size_t)n * KCAT + kc] = *(bf16x8*)u;
  } else if (c < 163840) {                       // zbf: 2048 x 64
    int i = c - 147456;
    int row = i >> 3, kc = (i & 7) * 8;
    unsigned short u[8];
#pragma unroll
    for (int e = 0; e < 8; ++e) u[e] = f2bf(z[(size_t)row * 64 + kc + e]);
    *(bf16x8*)&zbf[(size_t)row * 64 + kc] = *(bf16x8*)u;
  } else if (c < 165888) {                       // bias: 2048
    int n = c - 163840;
    bias[n] = bih[n] + bhh[n];
  } else if (c < 166912) {                       // wob: 16 x 512 (rows 8..15 = 0)
    int i = c - 165888;
    int r = i >> 6, kc = (i & 63) * 8;
    unsigned short u[8];
#pragma unroll
    for (int e = 0; e < 8; ++e) u[e] = (r < 8) ? f2bf(wout[(size_t)r * 512 + kc + e]) : (unsigned short)0;
    *(bf16x8*)&wob[(size_t)r * 512 + kc] = *(bf16x8*)u;
  }
}

// ---- step kernel. GATES: compute LSTM step t. PROJ: emit out[:, t-1, :]. ----
// grid 256 (GATES) or 16 (proj-only). 512 thr, 8 waves = 4 mq x 2 nh.
template <int GATES, int PROJ>
__global__ __launch_bounds__(512, 4) void k_step(
    const unsigned short* __restrict__ hprev, unsigned short* __restrict__ hnext,
    const unsigned short* __restrict__ wcat, const unsigned short* __restrict__ zbf,
    const unsigned short* __restrict__ wob, const float* __restrict__ bias,
    const float* __restrict__ bout, float* __restrict__ cst,
    float* __restrict__ out, int t) {
  __shared__ unsigned short Ab[2][128 * 64];     // h/z tile dbuf, 16 KB each
  __shared__ unsigned short Bb[2][144 * 64];     // W tile (+wob rows 128..143) dbuf, 18 KB each
  __shared__ unsigned short hO[128 * 40];        // h out staging

  const int bid = blockIdx.x;
  // XCD swizzle: consecutive bids round-robin XCDs; give each XCD 2 nt-slices.
  const int nt = GATES ? (((bid & 7) << 1) | ((bid >> 7) & 1)) : 0;
  const int bt = GATES ? ((bid >> 3) & 15) : bid;
  const int tid = threadIdx.x;
  const int lane = tid & 63;
  const int wv = tid >> 6;
  const int mq = wv >> 1, nh = wv & 1;
  const int cl = lane & 15, q8 = lane >> 4;
  const int b0 = bt * 128, j0 = nt * 32;

  // ---- staging addresses (lane-contiguous dest slots; XOR-swizzled source) ----
  const int rA = tid >> 3, sA = tid & 7;         // slot row/seg for s=0 plane
  const int xA = (sA ^ (rA & 7)) * 8;            // (rA+64)&7 == rA&7
  const unsigned short* srcA0 = hprev + (size_t)(b0 + rA) * HID + xA;
  const unsigned short* srcA1 = hprev + (size_t)(b0 + rA + 64) * HID + xA;
  const unsigned short* srcZ0 = zbf + (size_t)(b0 + rA) * 64 + xA;
  const unsigned short* srcZ1 = zbf + (size_t)(b0 + rA + 64) * 64 + xA;
  const int nB0 = (rA >> 5) * HID + j0 + (rA & 31);
  const int rB1 = rA + 64;
  const int nB1 = (rB1 >> 5) * HID + j0 + (rB1 & 31);
  const unsigned short* srcB0 = wcat + (size_t)nB0 * KCAT + xA;
  const unsigned short* srcB1 = wcat + (size_t)nB1 * KCAT + xA;
  const unsigned short* srcW = wob + (size_t)(tid >> 3) * HID + xA;  // tid<128 only
  unsigned short* dA0[2] = {&Ab[0][(wv * 64) * 8], &Ab[1][(wv * 64) * 8]};
  unsigned short* dA1[2] = {&Ab[0][(512 + wv * 64) * 8], &Ab[1][(512 + wv * 64) * 8]};
  unsigned short* dB0[2] = {&Bb[0][(wv * 64) * 8], &Bb[1][(wv * 64) * 8]};
  unsigned short* dB1[2] = {&Bb[0][(512 + wv * 64) * 8], &Bb[1][(512 + wv * 64) * 8]};
  unsigned short* dW[2]  = {&Bb[0][(1024 + wv * 64) * 8], &Bb[1][(1024 + wv * 64) * 8]};

#define STAGE_H(BUF, KK) do { \
    gl16(srcA0 + (KK) * 64, dA0[BUF]); gl16(srcA1 + (KK) * 64, dA1[BUF]); \
    if (GATES) { gl16(srcB0 + (KK) * 64, dB0[BUF]); gl16(srcB1 + (KK) * 64, dB1[BUF]); } \
    if (PROJ && tid < 128) gl16(srcW + (KK) * 64, dW[BUF]); } while (0)
#define STAGE_Z(BUF) do { \
    gl16(srcZ0, dA0[BUF]); gl16(srcZ1, dA1[BUF]); \
    gl16(srcB0 + 8 * 64, dB0[BUF]); gl16(srcB1 + 8 * 64, dB1[BUF]); } while (0)

  // ---- accumulators ----
  f32x4 acc[4][2];
  if (GATES) {
#pragma unroll
    for (int g = 0; g < 4; ++g) {
      float bv = bias[g * HID + j0 + nh * 16 + cl];
      f32x4 v = {bv, bv, bv, bv};
      acc[g][0] = v; acc[g][1] = v;
    }
  }
  f32x4 accp0 = {0, 0, 0, 0}, accp1 = {0, 0, 0, 0};
  if (PROJ) {
    float bo = (cl < 8) ? bout[cl] : 0.0f;
    f32x4 v = {bo, bo, bo, bo};
    accp0 = v; accp1 = v;
  }

  const int kkEnd = GATES ? 8 : 7;
  const int kk0 = (GATES && t == 0) ? 8 : 0;
  if (kk0 == 8) STAGE_Z(0); else STAGE_H(0, 0);
  __syncthreads();

  int bu = 0;
  for (int kk = kk0; kk <= kkEnd; ++kk) {
    if (kk < kkEnd) {
      if (kk + 1 == 8) STAGE_Z(bu ^ 1); else STAGE_H(bu ^ 1, kk + 1);
    }
    const unsigned short* Al = Ab[bu];
    const unsigned short* Bl = Bb[bu];
#pragma unroll
    for (int ks = 0; ks < 2; ++ks) {
      const int sx = ((ks * 4 + q8) ^ (cl & 7)) * 8;
      bf16x8 af0 = *(const bf16x8*)&Al[(mq * 32 + cl) * 64 + sx];
      bf16x8 af1 = *(const bf16x8*)&Al[(mq * 32 + 16 + cl) * 64 + sx];
      if (GATES) {
#pragma unroll
        for (int g = 0; g < 4; ++g) {
          bf16x8 bf = *(const bf16x8*)&Bl[(g * 32 + nh * 16 + cl) * 64 + sx];
          acc[g][0] = __builtin_amdgcn_mfma_f32_16x16x32_bf16(af0, bf, acc[g][0], 0, 0, 0);
          acc[g][1] = __builtin_amdgcn_mfma_f32_16x16x32_bf16(af1, bf, acc[g][1], 0, 0, 0);
        }
      }
      if (PROJ && nh == 0 && kk < 8) {
        bf16x8 wf = *(const bf16x8*)&Bl[(128 + cl) * 64 + sx];
        accp0 = __builtin_amdgcn_mfma_f32_16x16x32_bf16(af0, wf, accp0, 0, 0, 0);
        accp1 = __builtin_amdgcn_mfma_f32_16x16x32_bf16(af1, wf, accp1, 0, 0, 0);
      }
    }
    __syncthreads();
    bu ^= 1;
  }

  // ---- fused projection write: out[b][t-1][a], exclusive ownership ----
  if (PROJ && nh == 0 && cl < 8) {
    const int tt = t - 1;
#pragma unroll
    for (int r = 0; r < 4; ++r) {
      int b = b0 + mq * 32 + q8 * 4 + r;
      out[((size_t)b * 64 + tt) * 8 + cl] = accp0[r];
      out[((size_t)(b + 16) * 64 + tt) * 8 + cl] = accp1[r];
    }
  }

  if (GATES) {
    // ---- cell: c thread-contiguous in cst; h -> hO ----
    const size_t cbase = (((size_t)bt * 16 + nt) * 512 + tid) * 8;
    f32x4 c0 = {0, 0, 0, 0}, c1 = {0, 0, 0, 0};
    if (t > 0) { c0 = *(const f32x4*)&cst[cbase]; c1 = *(const f32x4*)&cst[cbase + 4]; }
#pragma unroll
    for (int fm = 0; fm < 2; ++fm) {
      f32x4 cold = fm ? c1 : c0;
      f32x4 cn;
#pragma unroll
      for (int r = 0; r < 4; ++r) {
        float iv = sigm(acc[0][fm][r]);
        float fv = sigm(acc[1][fm][r]);
        float gv = tanh_f(acc[2][fm][r]);
        float ov = sigm(acc[3][fm][r]);
        float cv = fv * cold[r] + iv * gv;
        cn[r] = cv;
        hO[(mq * 32 + fm * 16 + q8 * 4 + r) * 40 + nh * 16 + cl] = f2bf(ov * tanh_f(cv));
      }
      if (fm) c1 = cn; else c0 = cn;
    }
    *(f32x4*)&cst[cbase] = c0;
    *(f32x4*)&cst[cbase + 4] = c1;
    __syncthreads();

    // ---- h -> global ping-pong (always: t=63's h feeds the proj-only pass) ----
    int row = tid >> 2, sg4 = tid & 3;
    unsigned short tmp[8];
#pragma unroll
    for (int e = 0; e < 8; ++e) tmp[e] = hO[row * 40 + sg4 * 8 + e];
    *(int4*)&hnext[(size_t)(b0 + row) * HID + j0 + sg4 * 8] = *(int4*)tmp;
  }
#undef STAGE_H
#undef STAGE_Z
}

extern "C" void kernel_launch(void* const* d_in, const int* in_sizes, int n_in,
                              void* d_out, int out_size, void* d_ws, size_t ws_size,
                              hipStream_t stream) {
  const float* z    = (const float*)d_in[0];
  const float* wih  = (const float*)d_in[1];
  const float* whh  = (const float*)d_in[2];
  const float* bih  = (const float*)d_in[3];
  const float* bhh  = (const float*)d_in[4];
  const float* wout = (const float*)d_in[5];
  const float* bout = (const float*)d_in[6];
  float* out = (float*)d_out;

  char* ws = (char*)d_ws;
  unsigned short* wcat = (unsigned short*)(ws);              // 2,359,296
  unsigned short* zbf  = (unsigned short*)(ws + 2359296);    //   262,144
  float* bias          = (float*)(ws + 2621440);             //     8,192
  unsigned short* wob  = (unsigned short*)(ws + 2629632);    //    16,384
  unsigned short* h0   = (unsigned short*)(ws + 2646016);    // 2,097,152
  unsigned short* h1   = (unsigned short*)(ws + 4743168);    // 2,097,152
  float* cst           = (float*)(ws + 6840320);             // 4,194,304

  k_prep<<<dim3(652), dim3(256), 0, stream>>>(z, wih, whh, bih, bhh, wout,
                                              wcat, zbf, bias, wob);

  for (int t = 0; t < TSTEP; ++t) {
    const unsigned short* hp = (t & 1) ? h0 : h1;
    unsigned short* hn = (t & 1) ? h1 : h0;
    if (t == 0)
      k_step<1, 0><<<dim3(256), dim3(512), 0, stream>>>(hp, hn, wcat, zbf, wob, bias,
                                                        bout, cst, out, t);
    else
      k_step<1, 1><<<dim3(256), dim3(512), 0, stream>>>(hp, hn, wcat, zbf, wob, bias,
                                                        bout, cst, out, t);
  }
  // proj-only pass for t=63's h (reads h1, since t=63 wrote h1)
  k_step<0, 1><<<dim3(16), dim3(512), 0, stream>>>(h1, h0, wcat, zbf, wob, bias,
                                                   bout, cst, out, TSTEP);
}

// Round 8
// 946.761 us; speedup vs baseline: 1.6121x; 1.1582x over previous
//
#include <hip/hip_runtime.h>

// LSTM decoder B=2048, Z=64, A=8, H=512, T=64. Multi-launch, one kernel/step.
// gates = [h | z] @ [W_hh | W_ih_z]^T + bias, K = 576, bf16 MFMA 16x16x32.
// Round 8: 2 independent WGs per CU (grid 512 x 256 thr) so barrier drains of
// one WG overlap compute of the other. Per-wave structure identical to r7.

#define HID   512
#define TSTEP 64
#define KCAT  576

typedef __attribute__((ext_vector_type(8))) short bf16x8;
typedef __attribute__((ext_vector_type(4))) float f32x4;

__device__ inline unsigned short f2bf(float f) {
  unsigned int u = __builtin_bit_cast(unsigned int, f);
  unsigned int r = (u + 0x7fffu + ((u >> 16) & 1u)) >> 16;
  return (unsigned short)r;
}
__device__ inline float sigm(float x) { return 1.0f / (1.0f + __expf(-x)); }
__device__ inline float tanh_f(float x) { return 1.0f - 2.0f / (__expf(2.0f * x) + 1.0f); }

__device__ inline void gl16(const unsigned short* g, unsigned short* l) {
  __builtin_amdgcn_global_load_lds(
      (const __attribute__((address_space(1))) unsigned int*)g,
      (__attribute__((address_space(3))) unsigned int*)l, 16, 0, 0);
}

// ---- merged prep: wcat, zbf, bias, wob (W_out bf16, 16 rows, 8..15 zero) ----
__global__ void k_prep(const float* __restrict__ z, const float* __restrict__ wih,
                       const float* __restrict__ whh, const float* __restrict__ bih,
                       const float* __restrict__ bhh, const float* __restrict__ wout,
                       unsigned short* __restrict__ wcat, unsigned short* __restrict__ zbf,
                       float* __restrict__ bias, unsigned short* __restrict__ wob) {
  int c = blockIdx.x * 256 + threadIdx.x;
  if (c < 147456) {                              // wcat: 2048 rows x 72 chunks
    int n = c / 72, kc = (c % 72) * 8;
    unsigned short u[8];
#pragma unroll
    for (int e = 0; e < 8; ++e) {
      int k = kc + e;
      float v = (k < 512) ? whh[(size_t)n * 512 + k] : wih[(size_t)n * 72 + 8 + (k - 512)];
      u[e] = f2bf(v);
    }
    *(bf16x8*)&wcat[(size_t)n * KCAT + kc] = *(bf16x8*)u;
  } else if (c < 163840) {                       // zbf: 2048 x 64
    int i = c - 147456;
    int row = i >> 3, kc = (i & 7) * 8;
    unsigned short u[8];
#pragma unroll
    for (int e = 0; e < 8; ++e) u[e] = f2bf(z[(size_t)row * 64 + kc + e]);
    *(bf16x8*)&zbf[(size_t)row * 64 + kc] = *(bf16x8*)u;
  } else if (c < 165888) {                       // bias: 2048
    int n = c - 163840;
    bias[n] = bih[n] + bhh[n];
  } else if (c < 166912) {                       // wob: 16 x 512 (rows 8..15 = 0)
    int i = c - 165888;
    int r = i >> 6, kc = (i & 63) * 8;
    unsigned short u[8];
#pragma unroll
    for (int e = 0; e < 8; ++e) u[e] = (r < 8) ? f2bf(wout[(size_t)r * 512 + kc + e]) : (unsigned short)0;
    *(bf16x8*)&wob[(size_t)r * 512 + kc] = *(bf16x8*)u;
  }
}

// ---- step kernel. GATES: LSTM step t (grid 512). PROJ: emit out[:,t-1,:]. ----
// 256 thr, 4 waves = 2 mq x 2 nh. WG tile: 64 batch x 32 hid x 4 gates.
template <int GATES, int PROJ>
__global__ __launch_bounds__(256, 2) void k_step(
    const unsigned short* __restrict__ hprev, unsigned short* __restrict__ hnext,
    const unsigned short* __restrict__ wcat, const unsigned short* __restrict__ zbf,
    const unsigned short* __restrict__ wob, const float* __restrict__ bias,
    const float* __restrict__ bout, float* __restrict__ cst,
    float* __restrict__ out, int t) {
  __shared__ unsigned short Ab[2][64 * 64];      // h/z tile dbuf, 8 KB each
  __shared__ unsigned short Bb[2][144 * 64];     // W tile (+wob 128..143) dbuf, 18 KB each
  __shared__ unsigned short hO[64 * 40];         // h out staging

  const int bid = blockIdx.x;
  // XCD swizzle: bid&7 = XCD (round-robin); each XCD serves 2 nt slices.
  const int nt = GATES ? (((bid & 7) << 1) | ((bid >> 8) & 1)) : 0;
  const int bt = GATES ? ((bid >> 3) & 31) : bid;
  const int tid = threadIdx.x;
  const int lane = tid & 63;
  const int wv = tid >> 6;                       // 0..3
  const int mq = wv >> 1, nh = wv & 1;
  const int cl = lane & 15, q8 = lane >> 4;
  const int b0 = bt * 64, j0 = nt * 32;

  // ---- staging addresses (wave-linear dest slots; XOR-swizzled source) ----
  const int rA = tid >> 3;                       // 0..31
  const int xA = ((tid & 7) ^ (rA & 7)) * 8;     // (rA+32k)&7 == rA&7
  const unsigned short* srcA0 = hprev + (size_t)(b0 + rA) * HID + xA;
  const unsigned short* srcA1 = hprev + (size_t)(b0 + 32 + rA) * HID + xA;
  const unsigned short* srcZ0 = zbf + (size_t)(b0 + rA) * 64 + xA;
  const unsigned short* srcZ1 = zbf + (size_t)(b0 + 32 + rA) * 64 + xA;
  const unsigned short* srcB[4];
#pragma unroll
  for (int k = 0; k < 4; ++k) {
    int rB = k * 32 + rA;                        // B row 0..127 (gate k, hid rA&31)
    int n = (rB >> 5) * HID + j0 + (rB & 31);
    srcB[k] = wcat + (size_t)n * KCAT + xA;
  }
  const unsigned short* srcW = wob + (size_t)(tid >> 3) * HID + xA;   // tid<128

#define STAGE_H(BUF, KK) do { \
    gl16(srcA0 + (KK) * 64, &Ab[BUF][(wv * 64) * 8]); \
    gl16(srcA1 + (KK) * 64, &Ab[BUF][(256 + wv * 64) * 8]); \
    if (GATES) { _Pragma("unroll") for (int k = 0; k < 4; ++k) \
      gl16(srcB[k] + (KK) * 64, &Bb[BUF][(k * 256 + wv * 64) * 8]); } \
    if (PROJ && tid < 128) gl16(srcW + (KK) * 64, &Bb[BUF][(1024 + wv * 64) * 8]); \
  } while (0)
#define STAGE_Z(BUF) do { \
    gl16(srcZ0, &Ab[BUF][(wv * 64) * 8]); \
    gl16(srcZ1, &Ab[BUF][(256 + wv * 64) * 8]); \
    _Pragma("unroll") for (int k = 0; k < 4; ++k) \
      gl16(srcB[k] + 8 * 64, &Bb[BUF][(k * 256 + wv * 64) * 8]); \
  } while (0)

  // ---- accumulators ----
  f32x4 acc[4][2];
  if (GATES) {
#pragma unroll
    for (int g = 0; g < 4; ++g) {
      float bv = bias[g * HID + j0 + nh * 16 + cl];
      f32x4 v = {bv, bv, bv, bv};
      acc[g][0] = v; acc[g][1] = v;
    }
  }
  f32x4 accp0 = {0, 0, 0, 0}, accp1 = {0, 0, 0, 0};
  if (PROJ) {
    float bo = (cl < 8) ? bout[cl] : 0.0f;
    f32x4 v = {bo, bo, bo, bo};
    accp0 = v; accp1 = v;
  }

  const int kkEnd = GATES ? 8 : 7;
  const int kk0 = (GATES && t == 0) ? 8 : 0;
  if (kk0 == 8) STAGE_Z(0); else STAGE_H(0, 0);
  __syncthreads();

  int bu = 0;
  for (int kk = kk0; kk <= kkEnd; ++kk) {
    if (kk < kkEnd) {
      if (kk + 1 == 8) STAGE_Z(bu ^ 1); else STAGE_H(bu ^ 1, kk + 1);
    }
    const unsigned short* Al = Ab[bu];
    const unsigned short* Bl = Bb[bu];
#pragma unroll
    for (int ks = 0; ks < 2; ++ks) {
      const int sx = ((ks * 4 + q8) ^ (cl & 7)) * 8;
      bf16x8 af0 = *(const bf16x8*)&Al[(mq * 32 + cl) * 64 + sx];
      bf16x8 af1 = *(const bf16x8*)&Al[(mq * 32 + 16 + cl) * 64 + sx];
      if (GATES) {
#pragma unroll
        for (int g = 0; g < 4; ++g) {
          bf16x8 bf = *(const bf16x8*)&Bl[(g * 32 + nh * 16 + cl) * 64 + sx];
          acc[g][0] = __builtin_amdgcn_mfma_f32_16x16x32_bf16(af0, bf, acc[g][0], 0, 0, 0);
          acc[g][1] = __builtin_amdgcn_mfma_f32_16x16x32_bf16(af1, bf, acc[g][1], 0, 0, 0);
        }
      }
      if (PROJ && nh == 0 && kk < 8) {
        bf16x8 wf = *(const bf16x8*)&Bl[(128 + cl) * 64 + sx];
        accp0 = __builtin_amdgcn_mfma_f32_16x16x32_bf16(af0, wf, accp0, 0, 0, 0);
        accp1 = __builtin_amdgcn_mfma_f32_16x16x32_bf16(af1, wf, accp1, 0, 0, 0);
      }
    }
    __syncthreads();
    bu ^= 1;
  }

  // ---- fused projection write: out[b][t-1][a], exclusive ownership ----
  if (PROJ && nh == 0 && cl < 8) {
    const int tt = t - 1;
#pragma unroll
    for (int r = 0; r < 4; ++r) {
      int b = b0 + mq * 32 + q8 * 4 + r;
      out[((size_t)b * 64 + tt) * 8 + cl] = accp0[r];
      out[((size_t)(b + 16) * 64 + tt) * 8 + cl] = accp1[r];
    }
  }

  if (GATES) {
    // ---- cell: c thread-contiguous in cst; h -> hO ----
    const size_t cbase = ((size_t)bid * 256 + tid) * 8;
    f32x4 c0 = {0, 0, 0, 0}, c1 = {0, 0, 0, 0};
    if (t > 0) { c0 = *(const f32x4*)&cst[cbase]; c1 = *(const f32x4*)&cst[cbase + 4]; }
#pragma unroll
    for (int fm = 0; fm < 2; ++fm) {
      f32x4 cold = fm ? c1 : c0;
      f32x4 cn;
#pragma unroll
      for (int r = 0; r < 4; ++r) {
        float iv = sigm(acc[0][fm][r]);
        float fv = sigm(acc[1][fm][r]);
        float gv = tanh_f(acc[2][fm][r]);
        float ov = sigm(acc[3][fm][r]);
        float cv = fv * cold[r] + iv * gv;
        cn[r] = cv;
        hO[(mq * 32 + fm * 16 + q8 * 4 + r) * 40 + nh * 16 + cl] = f2bf(ov * tanh_f(cv));
      }
      if (fm) c1 = cn; else c0 = cn;
    }
    *(f32x4*)&cst[cbase] = c0;
    *(f32x4*)&cst[cbase + 4] = c1;
    __syncthreads();

    // ---- h -> global ping-pong (16B per thread, coalesced) ----
    int row = tid >> 2, sg4 = tid & 3;
    unsigned short tmp[8];
#pragma unroll
    for (int e = 0; e < 8; ++e) tmp[e] = hO[row * 40 + sg4 * 8 + e];
    *(int4*)&hnext[(size_t)(b0 + row) * HID + j0 + sg4 * 8] = *(int4*)tmp;
  }
#undef STAGE_H
#undef STAGE_Z
}

extern "C" void kernel_launch(void* const* d_in, const int* in_sizes, int n_in,
                              void* d_out, int out_size, void* d_ws, size_t ws_size,
                              hipStream_t stream) {
  const float* z    = (const float*)d_in[0];
  const float* wih  = (const float*)d_in[1];
  const float* whh  = (const float*)d_in[2];
  const float* bih  = (const float*)d_in[3];
  const float* bhh  = (const float*)d_in[4];
  const float* wout = (const float*)d_in[5];
  const float* bout = (const float*)d_in[6];
  float* out = (float*)d_out;

  char* ws = (char*)d_ws;
  unsigned short* wcat = (unsigned short*)(ws);              // 2,359,296
  unsigned short* zbf  = (unsigned short*)(ws + 2359296);    //   262,144
  float* bias          = (float*)(ws + 2621440);             //     8,192
  unsigned short* wob  = (unsigned short*)(ws + 2629632);    //    16,384
  unsigned short* h0   = (unsigned short*)(ws + 2646016);    // 2,097,152
  unsigned short* h1   = (unsigned short*)(ws + 4743168);    // 2,097,152
  float* cst           = (float*)(ws + 6840320);             // 4,194,304

  k_prep<<<dim3(652), dim3(256), 0, stream>>>(z, wih, whh, bih, bhh, wout,
                                              wcat, zbf, bias, wob);

  for (int t = 0; t < TSTEP; ++t) {
    const unsigned short* hp = (t & 1) ? h0 : h1;
    unsigned short* hn = (t & 1) ? h1 : h0;
    if (t == 0)
      k_step<1, 0><<<dim3(512), dim3(256), 0, stream>>>(hp, hn, wcat, zbf, wob, bias,
                                                        bout, cst, out, t);
    else
      k_step<1, 1><<<dim3(512), dim3(256), 0, stream>>>(hp, hn, wcat, zbf, wob, bias,
                                                        bout, cst, out, t);
  }
  // proj-only pass for t=63's h (t=63 wrote h1); 32 WGs cover 2048 batches
  k_step<0, 1><<<dim3(32), dim3(256), 0, stream>>>(h1, h0, wcat, zbf, wob, bias,
                                                   bout, cst, out, TSTEP);
}

// Round 9
// 926.673 us; speedup vs baseline: 1.6471x; 1.0217x over previous
//
#include <hip/hip_runtime.h>

// LSTM decoder B=2048, Z=64, A=8, H=512, T=64. Multi-launch, one kernel/step.
// gates = [h | z] @ [W_hh | W_ih_z]^T + bias, K = 576, bf16 MFMA 16x16x32.
// Round 9: counted-vmcnt 2-deep pipeline (T4): raw s_barrier + s_waitcnt
// vmcnt(6) — never drain to 0 mid-loop; chunk kk+2 staged while kk+1 flies.
// W_out staged once (reg->LDS, swizzled) so per-chunk loads are uniform (6).

#define HID   512
#define TSTEP 64
#define KCAT  576

typedef __attribute__((ext_vector_type(8))) short bf16x8;
typedef __attribute__((ext_vector_type(4))) float f32x4;

__device__ inline unsigned short f2bf(float f) {
  unsigned int u = __builtin_bit_cast(unsigned int, f);
  unsigned int r = (u + 0x7fffu + ((u >> 16) & 1u)) >> 16;
  return (unsigned short)r;
}
__device__ inline float sigm(float x) { return 1.0f / (1.0f + __expf(-x)); }
__device__ inline float tanh_f(float x) { return 1.0f - 2.0f / (__expf(2.0f * x) + 1.0f); }

__device__ inline void gl16(const unsigned short* g, unsigned short* l) {
  __builtin_amdgcn_global_load_lds(
      (const __attribute__((address_space(1))) unsigned int*)g,
      (__attribute__((address_space(3))) unsigned int*)l, 16, 0, 0);
}

// ---- merged prep: wcat (bf16 [W_hh|W_ih_z]), zbf, bias ----
__global__ void k_prep(const float* __restrict__ z, const float* __restrict__ wih,
                       const float* __restrict__ whh, const float* __restrict__ bih,
                       const float* __restrict__ bhh,
                       unsigned short* __restrict__ wcat, unsigned short* __restrict__ zbf,
                       float* __restrict__ bias) {
  int c = blockIdx.x * 256 + threadIdx.x;
  if (c < 147456) {                              // wcat: 2048 rows x 72 chunks
    int n = c / 72, kc = (c % 72) * 8;
    unsigned short u[8];
#pragma unroll
    for (int e = 0; e < 8; ++e) {
      int k = kc + e;
      float v = (k < 512) ? whh[(size_t)n * 512 + k] : wih[(size_t)n * 72 + 8 + (k - 512)];
      u[e] = f2bf(v);
    }
    *(bf16x8*)&wcat[(size_t)n * KCAT + kc] = *(bf16x8*)u;
  } else if (c < 163840) {                       // zbf: 2048 x 64
    int i = c - 147456;
    int row = i >> 3, kc = (i & 7) * 8;
    unsigned short u[8];
#pragma unroll
    for (int e = 0; e < 8; ++e) u[e] = f2bf(z[(size_t)row * 64 + kc + e]);
    *(bf16x8*)&zbf[(size_t)row * 64 + kc] = *(bf16x8*)u;
  } else if (c < 165888) {                       // bias: 2048
    int n = c - 163840;
    bias[n] = bih[n] + bhh[n];
  }
}

// ---- step kernel. GATES: LSTM step t (grid 512). PROJ: emit out[:,t-1,:]. ----
// 256 thr, 4 waves = 2 mq x 2 nh. WG tile: 64 batch x 32 hid x 4 gates.
template <int GATES, int PROJ>
__global__ __launch_bounds__(256, 2) void k_step(
    const unsigned short* __restrict__ hprev, unsigned short* __restrict__ hnext,
    const unsigned short* __restrict__ wcat, const unsigned short* __restrict__ zbf,
    const float* __restrict__ wout, const float* __restrict__ bias,
    const float* __restrict__ bout, float* __restrict__ cst,
    float* __restrict__ out, int t) {
  __shared__ unsigned short Ab[2][64 * 64];      // h/z tile dbuf, 8 KB each
  __shared__ unsigned short Bb[2][128 * 64];     // W tile dbuf, 16 KB each
  __shared__ unsigned short wo_lds[16 * 512];    // W_out bf16, swizzled, 16 KB
  __shared__ unsigned short hO[64 * 40];         // h out staging

  const int bid = blockIdx.x;
  const int nt = GATES ? (((bid & 7) << 1) | ((bid >> 8) & 1)) : 0;
  const int bt = GATES ? ((bid >> 3) & 31) : bid;
  const int tid = threadIdx.x;
  const int lane = tid & 63;
  const int wv = tid >> 6;                       // 0..3
  const int mq = wv >> 1, nh = wv & 1;
  const int cl = lane & 15, q8 = lane >> 4;
  const int b0 = bt * 64, j0 = nt * 32;

  // ---- staging addresses (wave-linear dest slots; XOR-swizzled source) ----
  const int rA = tid >> 3;                       // 0..31
  const int xA = ((tid & 7) ^ (rA & 7)) * 8;     // (rA+32k)&7 == rA&7
  const unsigned short* srcA0 = hprev + (size_t)(b0 + rA) * HID + xA;
  const unsigned short* srcA1 = hprev + (size_t)(b0 + 32 + rA) * HID + xA;
  const unsigned short* srcZ0 = zbf + (size_t)(b0 + rA) * 64 + xA;
  const unsigned short* srcZ1 = zbf + (size_t)(b0 + 32 + rA) * 64 + xA;
  const unsigned short* srcB[4];
#pragma unroll
  for (int k = 0; k < 4; ++k) {
    int rB = k * 32 + rA;
    int n = (rB >> 5) * HID + j0 + (rB & 31);
    srcB[k] = wcat + (size_t)n * KCAT + xA;
  }

  auto do_stage = [&](int buf, int kkv) {
    if (GATES) {
      if (kkv == 8) {
        gl16(srcZ0, &Ab[buf][(wv * 64) * 8]);
        gl16(srcZ1, &Ab[buf][(256 + wv * 64) * 8]);
      } else {
        gl16(srcA0 + kkv * 64, &Ab[buf][(wv * 64) * 8]);
        gl16(srcA1 + kkv * 64, &Ab[buf][(256 + wv * 64) * 8]);
      }
#pragma unroll
      for (int k = 0; k < 4; ++k)
        gl16(srcB[k] + kkv * 64, &Bb[buf][(k * 256 + wv * 64) * 8]);
    } else {
      gl16(srcA0 + kkv * 64, &Ab[buf][(wv * 64) * 8]);
      gl16(srcA1 + kkv * 64, &Ab[buf][(256 + wv * 64) * 8]);
    }
  };

  // ---- W_out -> LDS once (reg-staged, swizzled to match chunk reads) ----
  if (PROJ) {
    int r = tid >> 4, s0 = tid & 15;
#pragma unroll
    for (int i = 0; i < 4; ++i) {
      int s = s0 + i * 16;                       // k-seg 0..63
      unsigned short u[8] = {0, 0, 0, 0, 0, 0, 0, 0};
      if (r < 8) {
        const float* wp = wout + (size_t)r * 512 + s * 8;
        float4 f0 = *(const float4*)wp;
        float4 f1 = *(const float4*)(wp + 4);
        u[0] = f2bf(f0.x); u[1] = f2bf(f0.y); u[2] = f2bf(f0.z); u[3] = f2bf(f0.w);
        u[4] = f2bf(f1.x); u[5] = f2bf(f1.y); u[6] = f2bf(f1.z); u[7] = f2bf(f1.w);
      }
      int off = r * 512 + (s >> 3) * 64 + (((s & 7) ^ (r & 7)) * 8);
      *(bf16x8*)&wo_lds[off] = *(bf16x8*)u;
    }
  }

  // ---- accumulators ----
  f32x4 acc[4][2];
  if (GATES) {
#pragma unroll
    for (int g = 0; g < 4; ++g) {
      float bv = bias[g * HID + j0 + nh * 16 + cl];
      f32x4 v = {bv, bv, bv, bv};
      acc[g][0] = v; acc[g][1] = v;
    }
  }
  f32x4 accp0 = {0, 0, 0, 0}, accp1 = {0, 0, 0, 0};
  if (PROJ) {
    float bo = (cl < 8) ? bout[cl] : 0.0f;
    f32x4 v = {bo, bo, bo, bo};
    accp0 = v; accp1 = v;
  }

  // c prefetch (absorbed by first counted vmcnt)
  const size_t cbase = ((size_t)bid * 256 + tid) * 8;
  f32x4 c0 = {0, 0, 0, 0}, c1 = {0, 0, 0, 0};
  if (GATES && t > 0) { c0 = *(const f32x4*)&cst[cbase]; c1 = *(const f32x4*)&cst[cbase + 4]; }

  auto mfma_block = [&](int bu, int kkv) {
    const unsigned short* Al = Ab[bu];
    const unsigned short* Bl = Bb[bu];
#pragma unroll
    for (int ks = 0; ks < 2; ++ks) {
      const int sx = ((ks * 4 + q8) ^ (cl & 7)) * 8;
      bf16x8 af0 = *(const bf16x8*)&Al[(mq * 32 + cl) * 64 + sx];
      bf16x8 af1 = *(const bf16x8*)&Al[(mq * 32 + 16 + cl) * 64 + sx];
      if (GATES) {
#pragma unroll
        for (int g = 0; g < 4; ++g) {
          bf16x8 bf = *(const bf16x8*)&Bl[(g * 32 + nh * 16 + cl) * 64 + sx];
          acc[g][0] = __builtin_amdgcn_mfma_f32_16x16x32_bf16(af0, bf, acc[g][0], 0, 0, 0);
          acc[g][1] = __builtin_amdgcn_mfma_f32_16x16x32_bf16(af1, bf, acc[g][1], 0, 0, 0);
        }
      }
      if (PROJ && nh == 0 && kkv < 8) {
        bf16x8 wf = *(const bf16x8*)&wo_lds[cl * 512 + kkv * 64 + sx];
        accp0 = __builtin_amdgcn_mfma_f32_16x16x32_bf16(af0, wf, accp0, 0, 0, 0);
        accp1 = __builtin_amdgcn_mfma_f32_16x16x32_bf16(af1, wf, accp1, 0, 0, 0);
      }
    }
  };

#define MEMBAR() asm volatile("" ::: "memory")
#define HWBAR()  __builtin_amdgcn_s_barrier()

  if (GATES && t == 0) {
    do_stage(0, 8);                              // z-chunk only
    asm volatile("s_waitcnt vmcnt(0) lgkmcnt(0)" ::: "memory");
    HWBAR(); MEMBAR();
    mfma_block(0, 8);
  } else {
    do_stage(0, 0);
    do_stage(1, 1);
    if (GATES) asm volatile("s_waitcnt vmcnt(6) lgkmcnt(0)" ::: "memory");
    else       asm volatile("s_waitcnt vmcnt(2) lgkmcnt(0)" ::: "memory");
    HWBAR(); MEMBAR();
    const int kkEnd = GATES ? 8 : 7;
    for (int kk = 0;; ++kk) {
      mfma_block(kk & 1, kk);
      if (kk == kkEnd) break;
      MEMBAR(); HWBAR(); MEMBAR();               // BAR1: all waves done reading bu
      if (kk + 2 <= kkEnd) {
        do_stage(kk & 1, kk + 2);                // 2-deep prefetch into bu
        if (GATES) asm volatile("s_waitcnt vmcnt(6)" ::: "memory");
        else       asm volatile("s_waitcnt vmcnt(2)" ::: "memory");
      } else {
        asm volatile("s_waitcnt vmcnt(0)" ::: "memory");
      }
      MEMBAR(); HWBAR(); MEMBAR();               // BAR2: chunk kk+1 visible
    }
  }

  // ---- fused projection write: out[b][t-1][a], exclusive ownership ----
  if (PROJ && nh == 0 && cl < 8) {
    const int tt = t - 1;
#pragma unroll
    for (int r = 0; r < 4; ++r) {
      int b = b0 + mq * 32 + q8 * 4 + r;
      out[((size_t)b * 64 + tt) * 8 + cl] = accp0[r];
      out[((size_t)(b + 16) * 64 + tt) * 8 + cl] = accp1[r];
    }
  }

  if (GATES) {
    // ---- cell: c thread-contiguous in cst; h -> hO ----
#pragma unroll
    for (int fm = 0; fm < 2; ++fm) {
      f32x4 cold = fm ? c1 : c0;
      f32x4 cn;
#pragma unroll
      for (int r = 0; r < 4; ++r) {
        float iv = sigm(acc[0][fm][r]);
        float fv = sigm(acc[1][fm][r]);
        float gv = tanh_f(acc[2][fm][r]);
        float ov = sigm(acc[3][fm][r]);
        float cv = fv * cold[r] + iv * gv;
        cn[r] = cv;
        hO[(mq * 32 + fm * 16 + q8 * 4 + r) * 40 + nh * 16 + cl] = f2bf(ov * tanh_f(cv));
      }
      if (fm) c1 = cn; else c0 = cn;
    }
    *(f32x4*)&cst[cbase] = c0;
    *(f32x4*)&cst[cbase + 4] = c1;
    __syncthreads();

    // ---- h -> global ping-pong (16B per thread, coalesced) ----
    int row = tid >> 2, sg4 = tid & 3;
    unsigned short tmp[8];
#pragma unroll
    for (int e = 0; e < 8; ++e) tmp[e] = hO[row * 40 + sg4 * 8 + e];
    *(int4*)&hnext[(size_t)(b0 + row) * HID + j0 + sg4 * 8] = *(int4*)tmp;
  }
#undef MEMBAR
#undef HWBAR
}

extern "C" void kernel_launch(void* const* d_in, const int* in_sizes, int n_in,
                              void* d_out, int out_size, void* d_ws, size_t ws_size,
                              hipStream_t stream) {
  const float* z    = (const float*)d_in[0];
  const float* wih  = (const float*)d_in[1];
  const float* whh  = (const float*)d_in[2];
  const float* bih  = (const float*)d_in[3];
  const float* bhh  = (const float*)d_in[4];
  const float* wout = (const float*)d_in[5];
  const float* bout = (const float*)d_in[6];
  float* out = (float*)d_out;

  char* ws = (char*)d_ws;
  unsigned short* wcat = (unsigned short*)(ws);              // 2,359,296
  unsigned short* zbf  = (unsigned short*)(ws + 2359296);    //   262,144
  float* bias          = (float*)(ws + 2621440);             //     8,192
  unsigned short* h0   = (unsigned short*)(ws + 2629632);    // 2,097,152
  unsigned short* h1   = (unsigned short*)(ws + 4726784);    // 2,097,152
  float* cst           = (float*)(ws + 6823936);             // 4,194,304

  k_prep<<<dim3(648), dim3(256), 0, stream>>>(z, wih, whh, bih, bhh, wcat, zbf, bias);

  for (int t = 0; t < TSTEP; ++t) {
    const unsigned short* hp = (t & 1) ? h0 : h1;
    unsigned short* hn = (t & 1) ? h1 : h0;
    if (t == 0)
      k_step<1, 0><<<dim3(512), dim3(256), 0, stream>>>(hp, hn, wcat, zbf, wout, bias,
                                                        bout, cst, out, t);
    else
      k_step<1, 1><<<dim3(512), dim3(256), 0, stream>>>(hp, hn, wcat, zbf, wout, bias,
                                                        bout, cst, out, t);
  }
  // proj-only pass for t=63's h (t=63 wrote h1); 32 WGs cover 2048 batches
  k_step<0, 1><<<dim3(32), dim3(256), 0, stream>>>(h1, h0, wcat, zbf, wout, bias,
                                                   bout, cst, out, TSTEP);
}